// Round 12
// baseline (210.039 us; speedup 1.0000x reference)
//
#include <hip/hip_runtime.h>
#include <hip/hip_bf16.h>

typedef __bf16 bf16_t;
typedef __attribute__((ext_vector_type(8))) __bf16 bf16x8;
typedef __attribute__((ext_vector_type(4))) __bf16 bf16x4;
typedef __attribute__((ext_vector_type(4))) float f32x4;

#define MFMA16(a, b, c) __builtin_amdgcn_mfma_f32_16x16x32_bf16((a), (b), (c), 0, 0, 0)

// ---------------------------------------------------------------------------
// Kernel 1: QKV projection (unchanged). Q pre-scaled by (1/sqrt(128))*log2e;
// V written transposed as [b][h][t].
// ---------------------------------------------------------------------------
__global__ __launch_bounds__(256, 3) void proj_qkv(
    const float* __restrict__ X,
    const float* __restrict__ W0, const float* __restrict__ W1, const float* __restrict__ W2,
    bf16_t* __restrict__ O0, bf16_t* __restrict__ O1, bf16_t* __restrict__ O2)
{
    __shared__ __align__(16) char As[128 * 128];
    __shared__ __align__(16) char Bs[128 * 128];

    const int tid = threadIdx.x;
    const int wid = tid >> 6;
    const int lane = tid & 63;
    const int l15 = lane & 15, l4 = lane >> 4;
    const int wr = wid >> 1, wc = wid & 1;
    const int m0 = blockIdx.x * 128;

    const float* W = (blockIdx.y == 0) ? W0 : (blockIdx.y == 1 ? W1 : W2);

    const int r0 = tid >> 4;
    const int kq = tid & 15;
    const int swz = ((r0 & 7) << 4);

    f32x4 acc[4][4] = {};
    float4 xr[8];

    #pragma unroll
    for (int i = 0; i < 8; ++i)
        xr[i] = *(const float4*)(X + (size_t)(m0 + r0 + i * 16) * 1024 + kq * 4);

    for (int ks = 0; ks < 16; ++ks) {
        const int kb = ks * 64;
        #pragma unroll
        for (int i = 0; i < 8; ++i) {
            const int r = r0 + i * 16;
            bf16x4 av; av[0] = (bf16_t)xr[i].x; av[1] = (bf16_t)xr[i].y;
            av[2] = (bf16_t)xr[i].z; av[3] = (bf16_t)xr[i].w;
            *(bf16x4*)(As + r * 128 + ((kq * 8) ^ swz)) = av;
        }
        #pragma unroll
        for (int i = 0; i < 8; ++i) {
            const int r = r0 + i * 16;
            float4 wa = *(const float4*)(W + (size_t)r * 1024 + kb + kq * 4);
            bf16x4 wv; wv[0] = (bf16_t)wa.x; wv[1] = (bf16_t)wa.y;
            wv[2] = (bf16_t)wa.z; wv[3] = (bf16_t)wa.w;
            *(bf16x4*)(Bs + r * 128 + ((kq * 8) ^ swz)) = wv;
        }
        __syncthreads();
        if (ks < 15) {
            #pragma unroll
            for (int i = 0; i < 8; ++i)
                xr[i] = *(const float4*)(X + (size_t)(m0 + r0 + i * 16) * 1024 + kb + 64 + kq * 4);
        }
        #pragma unroll
        for (int kk = 0; kk < 64; kk += 32) {
            const int kbyte = 2 * kk + 16 * l4;
            bf16x8 af[4], bfr[4];
            #pragma unroll
            for (int mi = 0; mi < 4; ++mi) {
                int r = wr * 64 + mi * 16 + l15;
                af[mi] = *(const bf16x8*)(As + r * 128 + (kbyte ^ ((r & 7) << 4)));
            }
            #pragma unroll
            for (int ni = 0; ni < 4; ++ni) {
                int r = wc * 64 + ni * 16 + l15;
                bfr[ni] = *(const bf16x8*)(Bs + r * 128 + (kbyte ^ ((r & 7) << 4)));
            }
            #pragma unroll
            for (int mi = 0; mi < 4; ++mi)
                #pragma unroll
                for (int ni = 0; ni < 4; ++ni)
                    acc[mi][ni] = MFMA16(af[mi], bfr[ni], acc[mi][ni]);
        }
        __syncthreads();
    }

    if (blockIdx.y < 2) {
        const float sc = (blockIdx.y == 0) ? 0.12751754816f : 1.0f;  // 1/sqrt(128)*log2e
        bf16_t* O = (blockIdx.y == 0) ? O0 : O1;
        #pragma unroll
        for (int mi = 0; mi < 4; ++mi)
            #pragma unroll
            for (int ni = 0; ni < 4; ++ni) {
                int row = m0 + wr * 64 + mi * 16 + l4 * 4;
                int col = wc * 64 + ni * 16 + l15;
                #pragma unroll
                for (int r = 0; r < 4; ++r)
                    O[(size_t)(row + r) * 128 + col] = (bf16_t)(acc[mi][ni][r] * sc);
            }
    } else {
        #pragma unroll
        for (int mi = 0; mi < 4; ++mi)
            #pragma unroll
            for (int ni = 0; ni < 4; ++ni) {
                int row0 = m0 + wr * 64 + mi * 16 + l4 * 4;
                int col = wc * 64 + ni * 16 + l15;
                int bb = row0 >> 12, t0 = row0 & 4095;
                bf16x4 pk;
                #pragma unroll
                for (int r = 0; r < 4; ++r) pk[r] = (bf16_t)acc[mi][ni][r];
                *(bf16x4*)(O2 + ((size_t)bb << 19) + (size_t)col * 4096 + t0) = pk;
            }
    }
}

// ---------------------------------------------------------------------------
// Kernel 2: causal flash attention — occupancy-first variant.
// Equal-length blocks (atoms p=j, 127-j), waves kv-split mod 4, K prefetched
// from L2-resident global; V fragments read DIRECTLY from global at the PV
// point in two 4-fragment chunks (no LDS staging, no cross-tile V prefetch).
// LDS = 40KB (P 8KB + 32KB merge dump) -> 3 blocks/CU (12 waves/CU).
// Softmax: base-2, threshold-deferred max, denominator via ones-MFMA.
// ---------------------------------------------------------------------------
__global__ __launch_bounds__(256, 3) void attn_fwd(
    const bf16_t* __restrict__ Qb, const bf16_t* __restrict__ Kb,
    const bf16_t* __restrict__ Vtg, float* __restrict__ out, int Bn)
{
    // [0,8192): per-wave P (2KB each); merge stats overlay (P dead by merge).
    // [8192,40960): merge dump region, 8KB/wave per qs-pass.
    __shared__ __align__(16) char lds[40960];

    const int tid = threadIdx.x, wid = tid >> 6, lane = tid & 63;
    const int l15 = lane & 15, l4 = lane >> 4;

    const int blk = blockIdx.x;
    const int b = blk % Bn;              // batch == XCD -> K/V L2-resident
    const int j = blk / Bn;              // 0..63

    const size_t base = (size_t)b * 4096 * 128;
    const size_t baseVT = (size_t)b << 19;

    char* Pw = lds + wid * 2048;
    const int pswz = (l15 >> 1) & 3;     // P 16B-chunk XOR key

    // Constant all-ones A fragment: row-sum MFMA for the softmax denominator.
    bf16x8 aones;
    #pragma unroll
    for (int e = 0; e < 8; ++e) aones[e] = (bf16_t)1.0f;

    for (int seg = 0; seg < 2; ++seg) {
        const int p = seg ? (127 - j) : j;     // 32q atom index
        const int q0 = p << 5;
        const int nt = (p >= wid) ? ((p - wid) >> 2) + 1 : 0;  // my tiles: lt = wid+4i

        // Q fragments (B-operand): col q = q0+16qs+l15, k = 32kf+8l4+e.
        bf16x8 aq[2][4];
        #pragma unroll
        for (int qs = 0; qs < 2; ++qs)
            #pragma unroll
            for (int kf = 0; kf < 4; ++kf)
                aq[qs][kf] = *(const bf16x8*)(Qb + base
                    + (size_t)(q0 + 16 * qs + l15) * 128 + 32 * kf + 8 * l4);

        float mx[2] = {-1e30f, -1e30f};
        f32x4 ls_acc[2] = {};              // denominator accumulator (ones-MFMA)
        f32x4 o[2][8] = {};
        bf16x8 kreg[2][4];

        auto loadK = [&](int i) {
            const int kv0 = (wid + 4 * i) << 5;
            const bf16_t* kp = Kb + base + (size_t)(kv0 + l15) * 128 + 8 * l4;
            #pragma unroll
            for (int ni = 0; ni < 2; ++ni)
                #pragma unroll
                for (int kf = 0; kf < 4; ++kf)
                    kreg[ni][kf] = *(const bf16x8*)(kp + (size_t)ni * 2048 + kf * 32);
        };

        if (nt > 0) loadK(0);

        for (int i = 0; i < nt; ++i) {
            const int lt = wid + 4 * i;
            const int kv0 = lt << 5;

            // S^T = K * Q^T : D row = kv (16ni+4l4+r), col = q (l15).
            f32x4 sa[2][2];
            #pragma unroll
            for (int qs = 0; qs < 2; ++qs)
                #pragma unroll
                for (int ni = 0; ni < 2; ++ni) sa[qs][ni] = (f32x4){0.f, 0.f, 0.f, 0.f};
            __builtin_amdgcn_s_setprio(1);
            #pragma unroll
            for (int kf = 0; kf < 4; ++kf)
                #pragma unroll
                for (int ni = 0; ni < 2; ++ni) {
                    sa[0][ni] = MFMA16(kreg[ni][kf], aq[0][kf], sa[0][ni]);
                    sa[1][ni] = MFMA16(kreg[ni][kf], aq[1][kf], sa[1][ni]);
                }
            __builtin_amdgcn_s_setprio(0);

            if (i + 1 < nt) loadK(i + 1);   // prefetch: hidden under softmax+PV

            if (lt == p) {                  // only the diagonal tile masks
                #pragma unroll
                for (int qs = 0; qs < 2; ++qs) {
                    const int qg = q0 + 16 * qs + l15;
                    #pragma unroll
                    for (int ni = 0; ni < 2; ++ni)
                        #pragma unroll
                        for (int r = 0; r < 4; ++r)
                            if (kv0 + 16 * ni + 4 * l4 + r > qg) sa[qs][ni][r] = -1e30f;
                }
            }

            // Softmax, base-2, threshold-deferred max (THR=8 -> P <= 256).
            #pragma unroll
            for (int qs = 0; qs < 2; ++qs) {
                float tm = fmaxf(fmaxf(fmaxf(sa[qs][0][0], sa[qs][0][1]),
                                       fmaxf(sa[qs][0][2], sa[qs][0][3])),
                                 fmaxf(fmaxf(sa[qs][1][0], sa[qs][1][1]),
                                       fmaxf(sa[qs][1][2], sa[qs][1][3])));
                if (__any(tm > mx[qs] + 8.0f)) {   // rare: full reduce + rescale
                    tm = fmaxf(tm, __shfl_xor(tm, 16, 64));
                    tm = fmaxf(tm, __shfl_xor(tm, 32, 64));
                    const float mnew = fmaxf(mx[qs], tm);
                    const float c = exp2f(mx[qs] - mnew);
                    f32x4 lt4 = ls_acc[qs];
                    lt4[0] *= c; lt4[1] *= c; lt4[2] *= c; lt4[3] *= c;
                    ls_acc[qs] = lt4;
                    #pragma unroll
                    for (int mf = 0; mf < 8; ++mf) {
                        f32x4 t = o[qs][mf];
                        t[0] *= c; t[1] *= c; t[2] *= c; t[3] *= c;
                        o[qs][mf] = t;
                    }
                    mx[qs] = mnew;
                }
                // P = exp2(S - mx); bounded by 2^8. No sum here (ones-MFMA).
                #pragma unroll
                for (int ni = 0; ni < 2; ++ni) {
                    bf16x4 pv;
                    #pragma unroll
                    for (int r = 0; r < 4; ++r)
                        pv[r] = (bf16_t)exp2f(sa[qs][ni][r] - mx[qs]);
                    *(bf16x4*)(Pw + (16 * qs + l15) * 64
                               + (((2 * ni + (l4 >> 1)) ^ pswz) << 4) + 8 * (l4 & 1)) = pv;
                }
            }

            // O^T += V^T * P^T with V straight from L2-resident global.
            // A-fragment: row h = 16mf+l15, k = 8l4+e  ->  Vt[h][kv0+8l4+e].
            bf16x8 pa0 = *(const bf16x8*)(Pw + l15 * 64 + ((l4 ^ pswz) << 4));
            bf16x8 pa1 = *(const bf16x8*)(Pw + (16 + l15) * 64 + ((l4 ^ pswz) << 4));
            ls_acc[0] = MFMA16(aones, pa0, ls_acc[0]);
            ls_acc[1] = MFMA16(aones, pa1, ls_acc[1]);
            const bf16_t* vp = Vtg + baseVT + (size_t)l15 * 4096 + kv0 + 8 * l4;
            #pragma unroll
            for (int hf = 0; hf < 2; ++hf) {
                bf16x8 av[4];
                #pragma unroll
                for (int m = 0; m < 4; ++m)
                    av[m] = *(const bf16x8*)(vp + (size_t)(16 * (4 * hf + m)) * 4096);
                __builtin_amdgcn_s_setprio(1);
                #pragma unroll
                for (int m = 0; m < 4; ++m) {
                    o[0][4 * hf + m] = MFMA16(av[m], pa0, o[0][4 * hf + m]);
                    o[1][4 * hf + m] = MFMA16(av[m], pa1, o[1][4 * hf + m]);
                }
                __builtin_amdgcn_s_setprio(0);
            }
        }

        // ---- per-atom merge of the 4 kv-split states (two qs-passes) ----
        #pragma unroll
        for (int qs = 0; qs < 2; ++qs) {
            __syncthreads();    // all waves done with P (qs=0) / prior pass
            #pragma unroll
            for (int mf = 0; mf < 8; ++mf)
                *(f32x4*)(lds + 8192 + wid * 8192 + mf * 1024 + lane * 16) = o[qs][mf];
            if (l4 == 0)
                *(float2*)(lds + wid * 256 + l15 * 8)
                    = make_float2(mx[qs], ls_acc[qs][0]);
            __syncthreads();
            float mw[4], lw[4];
            #pragma unroll
            for (int w = 0; w < 4; ++w) {
                float2 st = *(const float2*)(lds + w * 256 + l15 * 8);
                mw[w] = st.x; lw[w] = st.y;
            }
            const float M = fmaxf(fmaxf(mw[0], mw[1]), fmaxf(mw[2], mw[3]));
            float cw[4], L = 0.f;
            #pragma unroll
            for (int w = 0; w < 4; ++w) { cw[w] = exp2f(mw[w] - M); L += lw[w] * cw[w]; }
            const float inv = 1.f / L;
            #pragma unroll
            for (int mm = 0; mm < 2; ++mm) {
                const int mf = 2 * wid + mm;    // this wave's h-slice
                f32x4 acc = (f32x4){0.f, 0.f, 0.f, 0.f};
                #pragma unroll
                for (int w = 0; w < 4; ++w) {
                    f32x4 v = *(const f32x4*)(lds + 8192 + w * 8192 + mf * 1024 + lane * 16);
                    #pragma unroll
                    for (int e = 0; e < 4; ++e) acc[e] += v[e] * cw[w];
                }
                #pragma unroll
                for (int e = 0; e < 4; ++e) acc[e] *= inv;
                float* op = out + ((size_t)b * 4096 + q0 + 16 * qs + l15) * 128 + 16 * mf + 4 * l4;
                *(f32x4*)op = acc;
            }
        }
        __syncthreads();   // P region safe for next atom
    }
}

extern "C" void kernel_launch(void* const* d_in, const int* in_sizes, int n_in,
                              void* d_out, int out_size, void* d_ws, size_t ws_size,
                              hipStream_t stream) {
    const float* X  = (const float*)d_in[0];
    const float* Wq = (const float*)d_in[1];
    const float* Wk = (const float*)d_in[2];
    const float* Wv = (const float*)d_in[3];
    float* out = (float*)d_out;

    const int M = in_sizes[0] / 1024;      // B*T = 32768
    const int Bn = M / 4096;               // 8

    bf16_t* Qb  = (bf16_t*)d_ws;
    bf16_t* KbP = Qb + (size_t)M * 128;
    bf16_t* VtP = KbP + (size_t)M * 128;   // transposed: [b][128][4096]

    proj_qkv<<<dim3(M / 128, 3), 256, 0, stream>>>(X, Wq, Wk, Wv, Qb, KbP, VtP);
    attn_fwd<<<dim3(64 * Bn), 256, 0, stream>>>(Qb, KbP, VtP, out, Bn);
}